// Round 3
// baseline (3307.579 us; speedup 1.0000x reference)
//
#include <hip/hip_runtime.h>
#include <hip/hip_bf16.h>

#define T_ 64
#define B_ 64
#define E_ 512
#define H_ 1024
#define V_ 10000
#define TB 4096   // T_*B_
#define BH 65536  // B_*H_

typedef unsigned short u16;
typedef unsigned int u32;
typedef __attribute__((ext_vector_type(8))) short short8v;
typedef __attribute__((ext_vector_type(4))) float f32x4;

__device__ inline f32x4 mfma_bf16(short8v a, short8v b, f32x4 c) {
  return __builtin_amdgcn_mfma_f32_16x16x32_bf16(a, b, c, 0, 0, 0);
}

__device__ inline u16 f2bf(float f) {
  unsigned u = __float_as_uint(f);
  unsigned r = (u + 0x7fffu + ((u >> 16) & 1u)) >> 16;
  return (u16)r;
}
__device__ inline float bf2f(u16 h) { return __uint_as_float(((unsigned)h) << 16); }

// ---------------- prep ----------------

// one grid-stride kernel converts/packs ALL weights
__global__ void k_prepall(const float* __restrict__ Wr0, const float* __restrict__ Wz0,
                          const float* __restrict__ Wh0, const float* __restrict__ Ur,
                          const float* __restrict__ Uz, const float* __restrict__ Uh,
                          const float* __restrict__ WrR, const float* __restrict__ WzR,
                          const float* __restrict__ WhR, const float* __restrict__ Wout,
                          u16* __restrict__ W0cat, u16* __restrict__ U0cat,
                          u16* __restrict__ U1W, u16* __restrict__ Woutb) {
  const int HE = H_ * E_;  // 2^19
  const int HH = H_ * H_;  // 2^20
  const size_t n0 = 3u * (size_t)HE;        // 1572864
  const size_t n1 = n0 + 3u * (size_t)HH;   // 4718592
  const size_t n2 = n1 + 3072u * 2048u;     // 11010048
  const size_t n3 = n2 + (size_t)V_ * H_;   // 21250048
  size_t i = (size_t)blockIdx.x * 256 + threadIdx.x;
  const size_t stride = (size_t)gridDim.x * 256;
  for (; i < n3; i += stride) {
    if (i < n0) {
      int g = (int)(i >> 19), off = (int)(i & (HE - 1));
      const float* s = g == 0 ? Wr0 : (g == 1 ? Wz0 : Wh0);
      W0cat[i] = f2bf(s[off]);
    } else if (i < n1) {
      size_t j = i - n0;
      int g = (int)(j >> 20), off = (int)(j & (HH - 1));
      const float* s = g == 0 ? Ur : (g == 1 ? Uz : Uh);
      U0cat[j] = f2bf(s[off]);
    } else if (i < n2) {
      size_t k = i - n1;
      int row = (int)(k >> 11), kk = (int)(k & 2047);
      int g = row >> 10, jj = row & 1023;
      const float* su = g == 0 ? Ur : (g == 1 ? Uz : Uh);
      const float* sw = g == 0 ? WrR : (g == 1 ? WzR : WhR);
      float v = (kk < 1024) ? su[(size_t)HH + (size_t)jj * 1024 + kk]
                            : sw[(size_t)jj * 1024 + (kk - 1024)];
      U1W[k] = f2bf(v);
    } else {
      size_t m = i - n2;
      Woutb[m] = f2bf(Wout[m]);
    }
  }
}

__global__ void k_gather(const int* __restrict__ idx, const float* __restrict__ emb,
                         u16* __restrict__ xbf) {
  int i = blockIdx.x * 256 + threadIdx.x;  // over TB*E_
  int row = i >> 9, e = i & 511;
  xbf[i] = f2bf(emb[(size_t)idx[row] * E_ + e]);
}

__global__ void k_bias(const float* __restrict__ bur, const float* __restrict__ buz,
                       const float* __restrict__ buh, const float* __restrict__ brR,
                       const float* __restrict__ bzR, const float* __restrict__ bhR,
                       float* __restrict__ bias0, float* __restrict__ bias1) {
  int j = blockIdx.x * 256 + threadIdx.x;  // 0..3071
  int seg = j >> 10, col = j & 1023;
  float b0, b1;
  if (seg == 0)      { b0 = bur[col]; b1 = brR[col] + bur[H_ + col]; }
  else if (seg == 1) { b0 = buz[col]; b1 = bzR[col] + buz[H_ + col]; }
  else               { b0 = buh[col]; b1 = bhR[col] + buh[H_ + col]; }
  bias0[j] = b0; bias1[j] = b1;
}

// init packed hist slabs at t=0: dst[(j>>4)*1024 + row*16 + (j&15)]
__global__ void k_init(const float* __restrict__ hidden, u16* __restrict__ h0P,
                       u16* __restrict__ h1P) {
  int i = blockIdx.x * 256 + threadIdx.x;  // 0..65535
  int row = i >> 10, j = i & 1023;
  int dst = ((j >> 4) << 10) + (row << 4) + (j & 15);
  h0P[dst] = f2bf(hidden[i]);
  h1P[dst] = f2bf(hidden[BH + i]);
}

// ---------------- GEMM 1: X = x_emb @ W0cat^T + bias0, packed-X bf16 out ----------------

__global__ __launch_bounds__(256, 2) void k_gemmX(const u16* __restrict__ A,
                                                  const u16* __restrict__ Wt,
                                                  const float* __restrict__ bias,
                                                  u16* __restrict__ XP) {
  const int m0 = blockIdx.x * 128, n0 = blockIdx.y * 128;
  const int wid = threadIdx.x >> 6, lane = threadIdx.x & 63;
  const int wm = wid >> 1, wn = wid & 1;
  const int lrow = lane & 15, lk = (lane >> 4) * 8;
  f32x4 acc[4][4] = {};
  const u16* Ab = A + (size_t)(m0 + wm * 64 + lrow) * 512 + lk;
  const u16* Wb = Wt + (size_t)(n0 + wn * 64 + lrow) * 512 + lk;
  for (int ks = 0; ks < 512; ks += 32) {
    short8v a[4], b[4];
#pragma unroll
    for (int f = 0; f < 4; f++) a[f] = *(const short8v*)(Ab + (size_t)f * 16 * 512 + ks);
#pragma unroll
    for (int f = 0; f < 4; f++) b[f] = *(const short8v*)(Wb + (size_t)f * 16 * 512 + ks);
#pragma unroll
    for (int i = 0; i < 4; i++)
#pragma unroll
      for (int j = 0; j < 4; j++) acc[i][j] = mfma_bf16(a[i], b[j], acc[i][j]);
  }
  const int drow0 = (lane >> 4) * 4, dcol = lane & 15;
#pragma unroll
  for (int i = 0; i < 4; i++)
#pragma unroll
    for (int j = 0; j < 4; j++) {
      int col = n0 + wn * 64 + j * 16 + dcol;
      float bv = bias[col];
      int g = col >> 10, bid = (col & 1023) >> 4, cc = col & 15;
#pragma unroll
      for (int v = 0; v < 4; v++) {
        int row = m0 + wm * 64 + i * 16 + drow0 + v;
        int t = row >> 6, rr = row & 63;
        XP[(((size_t)t * 64 + bid) * 64 + rr) * 48 + g * 16 + cc] = f2bf(acc[i][j][v] + bv);
      }
    }
}

// ---------------- GEMM 2: logits = h1P(packed) @ Woutb^T + bout ----------------

__global__ __launch_bounds__(256, 2) void k_gemmL(const u16* __restrict__ AP,
                                                  const u16* __restrict__ Wt,
                                                  const float* __restrict__ bias,
                                                  float* __restrict__ C) {
  const int m0 = blockIdx.x * 128, n0 = blockIdx.y * 128;
  const int wid = threadIdx.x >> 6, lane = threadIdx.x & 63;
  const int wm = wid >> 1, wn = wid & 1;
  const int lrow = lane & 15, lk = (lane >> 4) * 8;
  const int lkb = lk >> 4, lkc = lk & 15;
  f32x4 acc[4][4] = {};
  const int rowhi = (m0 + wm * 64) >> 6;  // slab index
  const u16* Ab = AP + (size_t)rowhi * BH + (size_t)lkb * 1024 + lrow * 16 + lkc;
  const u16* Wb = Wt + (size_t)(n0 + wn * 64 + lrow) * 1024 + lk;
  bool nvalid[4];
#pragma unroll
  for (int f = 0; f < 4; f++) nvalid[f] = (n0 + wn * 64 + f * 16 + lrow) < V_;
  const short8v zv = {};
  for (int ks = 0; ks < 1024; ks += 32) {
    short8v a[4], b[4];
#pragma unroll
    for (int f = 0; f < 4; f++) a[f] = *(const short8v*)(Ab + ks * 64 + f * 256);
#pragma unroll
    for (int f = 0; f < 4; f++)
      b[f] = nvalid[f] ? *(const short8v*)(Wb + (size_t)f * 16 * 1024 + ks) : zv;
#pragma unroll
    for (int i = 0; i < 4; i++)
#pragma unroll
      for (int j = 0; j < 4; j++) acc[i][j] = mfma_bf16(a[i], b[j], acc[i][j]);
  }
  const int drow0 = (lane >> 4) * 4, dcol = lane & 15;
#pragma unroll
  for (int i = 0; i < 4; i++)
#pragma unroll
    for (int j = 0; j < 4; j++) {
      int col = n0 + wn * 64 + j * 16 + dcol;
      if (col >= V_) continue;
      float bv = bias[col];
#pragma unroll
      for (int v = 0; v < 4; v++) {
        int row = m0 + wm * 64 + i * 16 + drow0 + v;
        C[(size_t)row * V_ + col] = acc[i][j][v] + bv;
      }
    }
}

// ---------------- fused 2-layer pipelined recurrence (no LDS) ----------------
// 128 blocks x 256 thr. Blocks 0-63: layer 0 (t=p); 64-127: layer 1 (t=p-1).
// Block owns 16 output cols; wave w owns rows w*16..w*16+15 for FULL K.
// z, master-h(fp32), X live in registers (D-frag mapping identical across stages).
// Cross-block data in packed per-block tiles [t][blk][row 64][col 16] bf16,
// published as contiguous u32 agent-scope stores.

__device__ inline void gbar(int* bar, int& phase) {
  asm volatile("s_waitcnt vmcnt(0)" ::: "memory");
  __syncthreads();
  ++phase;
  const int tid = threadIdx.x;
  const int gbid = blockIdx.x;
  if (tid == 0)
    __hip_atomic_fetch_add(bar + (gbid & 7) * 32, 1, __ATOMIC_RELAXED,
                           __HIP_MEMORY_SCOPE_AGENT);
  if (gbid == 0) {
    if (tid < 64) {
      const int need = 16 * phase;
      bool done;
      do {
        int c = (tid < 8) ? __hip_atomic_load(bar + tid * 32, __ATOMIC_RELAXED,
                                              __HIP_MEMORY_SCOPE_AGENT)
                          : need;
        done = __all(c >= need);
        if (!done) __builtin_amdgcn_s_sleep(1);
      } while (!done);
      if (tid == 0)
        __hip_atomic_store(bar + 512, phase, __ATOMIC_RELAXED, __HIP_MEMORY_SCOPE_AGENT);
    }
  } else if (tid == 0) {
    while (__hip_atomic_load(bar + 512, __ATOMIC_RELAXED, __HIP_MEMORY_SCOPE_AGENT) < phase)
      __builtin_amdgcn_s_sleep(1);
  }
  __syncthreads();
}

__global__ __launch_bounds__(256, 1) void k_recur2(
    const u16* __restrict__ U0, const u16* __restrict__ U1W,
    const u16* __restrict__ XP, const float* __restrict__ bias1,
    const float* __restrict__ hidden,
    u16* __restrict__ h0P, u16* __restrict__ h1P,
    u16* __restrict__ r0P, u16* __restrict__ r1P,
    int* __restrict__ bar, float* __restrict__ hfin) {
  const int tid = threadIdx.x, gbid = blockIdx.x;
  const int lay = gbid >> 6, bid = gbid & 63;
  const int wid = tid >> 6, lane = tid & 63;
  const int lrow = lane & 15, lk = (lane >> 4) * 8;     // A/B load mapping
  const int lkb = lk >> 4, lkc = lk & 15;               // packed-A: blk+col offsets
  const int drow0 = (lane >> 4) * 4, dcol = lane & 15;  // D mapping
  const int jr = bid * 16;
  const int KL = lay ? 2048 : 1024;
  const u16* Wg = lay ? U1W : U0;
  u16* histL = lay ? h1P : h0P;
  u16* rhL = lay ? r1P : r0P;

  const u16* Wr = Wg + (size_t)(jr + lrow) * KL + lk;
  const u16* Wz = Wr + (size_t)1024 * KL;
  const u16* Wh = Wr + (size_t)2048 * KL;

  const int orow = wid * 16 + drow0;  // output row base (this lane: rows orow..orow+3)
  const int arow = wid * 16 + lrow;   // A-operand row for loads

  float hreg[4];
#pragma unroll
  for (int v = 0; v < 4; v++)
    hreg[v] = hidden[(size_t)lay * BH + (size_t)(orow + v) * 1024 + jr + dcol];

  float bR = 0.f, bZ = 0.f, bH = 0.f;
  if (lay) {
    bR = bias1[jr + dcol];
    bZ = bias1[1024 + jr + dcol];
    bH = bias1[2048 + jr + dcol];
  }

  int phase = 0;
  for (int p = 0; p <= T_; p++) {
    const int t = lay ? (p - 1) : p;
    const bool act = (t >= 0) && (t < T_);
    float zreg[4], xh[4];
    if (act) {
      // preload X (layer 0) for all three gates
      float xr[4], xz[4];
      if (!lay) {
        const u16* xb = XP + (((size_t)t * 64 + bid) * 64 + orow) * 48 + dcol;
#pragma unroll
        for (int v = 0; v < 4; v++) {
          xr[v] = bf2f(xb[v * 48]);
          xz[v] = bf2f(xb[v * 48 + 16]);
          xh[v] = bf2f(xb[v * 48 + 32]);
        }
      } else {
#pragma unroll
        for (int v = 0; v < 4; v++) { xr[v] = bR; xz[v] = bZ; xh[v] = bH; }
      }
      // ---------- stage A: r,z gates ----------
      f32x4 accr[2] = {}, accz[2] = {};
      if (!lay) {
        const u16* Ab = h0P + (size_t)t * BH + (size_t)lkb * 1024 + arow * 16 + lkc;
        for (int kk = 0; kk < 1024; kk += 64) {
          short8v a0 = *(const short8v*)(Ab + kk * 64);
          short8v a1 = *(const short8v*)(Ab + kk * 64 + 2048);
          accr[0] = mfma_bf16(a0, *(const short8v*)(Wr + kk), accr[0]);
          accz[0] = mfma_bf16(a0, *(const short8v*)(Wz + kk), accz[0]);
          accr[1] = mfma_bf16(a1, *(const short8v*)(Wr + kk + 32), accr[1]);
          accz[1] = mfma_bf16(a1, *(const short8v*)(Wz + kk + 32), accz[1]);
        }
      } else {
        const u16* Ab1 = h1P + (size_t)t * BH + (size_t)lkb * 1024 + arow * 16 + lkc;
        const u16* Ab0 = h0P + (size_t)(t + 1) * BH + (size_t)lkb * 1024 + arow * 16 + lkc;
        for (int kk = 0; kk < 1024; kk += 64) {
          short8v a0 = *(const short8v*)(Ab1 + kk * 64);
          short8v a1 = *(const short8v*)(Ab1 + kk * 64 + 2048);
          accr[0] = mfma_bf16(a0, *(const short8v*)(Wr + kk), accr[0]);
          accz[0] = mfma_bf16(a0, *(const short8v*)(Wz + kk), accz[0]);
          accr[1] = mfma_bf16(a1, *(const short8v*)(Wr + kk + 32), accr[1]);
          accz[1] = mfma_bf16(a1, *(const short8v*)(Wz + kk + 32), accz[1]);
        }
        for (int kk = 0; kk < 1024; kk += 64) {
          short8v a0 = *(const short8v*)(Ab0 + kk * 64);
          short8v a1 = *(const short8v*)(Ab0 + kk * 64 + 2048);
          accr[0] = mfma_bf16(a0, *(const short8v*)(Wr + 1024 + kk), accr[0]);
          accz[0] = mfma_bf16(a0, *(const short8v*)(Wz + 1024 + kk), accz[0]);
          accr[1] = mfma_bf16(a1, *(const short8v*)(Wr + 1024 + kk + 32), accr[1]);
          accz[1] = mfma_bf16(a1, *(const short8v*)(Wz + 1024 + kk + 32), accz[1]);
        }
      }
      f32x4 sr = accr[0] + accr[1];
      f32x4 sz = accz[0] + accz[1];
      u16* rtile = rhL + (size_t)t * BH + (size_t)bid * 1024;
#pragma unroll
      for (int v = 0; v < 4; v++) {
        float r = 1.f / (1.f + __expf(-(sr[v] + xr[v])));
        float z = 1.f / (1.f + __expf(-(sz[v] + xz[v])));
        zreg[v] = z;
        u16 me = f2bf(r * hreg[v]);
        int other = __shfl_xor((int)me, 1, 64);
        if (!(dcol & 1)) {
          u32 pk = (u32)me | ((u32)(u16)other << 16);
          __hip_atomic_store((u32*)(rtile + (orow + v) * 16 + dcol), pk,
                             __ATOMIC_RELAXED, __HIP_MEMORY_SCOPE_AGENT);
        }
      }
    }
    gbar(bar, phase);
    if (act) {
      // ---------- stage B: candidate + state update ----------
      f32x4 acch[2] = {};
      if (!lay) {
        const u16* Ab = r0P + (size_t)t * BH + (size_t)lkb * 1024 + arow * 16 + lkc;
        for (int kk = 0; kk < 1024; kk += 64) {
          short8v a0 = *(const short8v*)(Ab + kk * 64);
          short8v a1 = *(const short8v*)(Ab + kk * 64 + 2048);
          acch[0] = mfma_bf16(a0, *(const short8v*)(Wh + kk), acch[0]);
          acch[1] = mfma_bf16(a1, *(const short8v*)(Wh + kk + 32), acch[1]);
        }
      } else {
        const u16* Ab1 = r1P + (size_t)t * BH + (size_t)lkb * 1024 + arow * 16 + lkc;
        const u16* Ab0 = h0P + (size_t)(t + 1) * BH + (size_t)lkb * 1024 + arow * 16 + lkc;
        for (int kk = 0; kk < 1024; kk += 64) {
          short8v a0 = *(const short8v*)(Ab1 + kk * 64);
          short8v a1 = *(const short8v*)(Ab1 + kk * 64 + 2048);
          acch[0] = mfma_bf16(a0, *(const short8v*)(Wh + kk), acch[0]);
          acch[1] = mfma_bf16(a1, *(const short8v*)(Wh + kk + 32), acch[1]);
        }
        for (int kk = 0; kk < 1024; kk += 64) {
          short8v a0 = *(const short8v*)(Ab0 + kk * 64);
          short8v a1 = *(const short8v*)(Ab0 + kk * 64 + 2048);
          acch[0] = mfma_bf16(a0, *(const short8v*)(Wh + 1024 + kk), acch[0]);
          acch[1] = mfma_bf16(a1, *(const short8v*)(Wh + 1024 + kk + 32), acch[1]);
        }
      }
      f32x4 sh = acch[0] + acch[1];
      u16* htile = histL + (size_t)(t + 1) * BH + (size_t)bid * 1024;
#pragma unroll
      for (int v = 0; v < 4; v++) {
        float th = tanhf(sh[v] + xh[v]);
        float hn = (1.f - zreg[v]) * hreg[v] + zreg[v] * th;
        hreg[v] = hn;
        u16 me = f2bf(hn);
        int other = __shfl_xor((int)me, 1, 64);
        if (!(dcol & 1)) {
          u32 pk = (u32)me | ((u32)(u16)other << 16);
          __hip_atomic_store((u32*)(htile + (orow + v) * 16 + dcol), pk,
                             __ATOMIC_RELAXED, __HIP_MEMORY_SCOPE_AGENT);
        }
        if (t == T_ - 1)
          hfin[(size_t)lay * BH + (size_t)(orow + v) * 1024 + jr + dcol] = hn;
      }
    }
    gbar(bar, phase);
  }
}

// ---------------- launcher ----------------

extern "C" void kernel_launch(void* const* d_in, const int* in_sizes, int n_in,
                              void* d_out, int out_size, void* d_ws, size_t ws_size,
                              hipStream_t stream) {
  const int* inputs = (const int*)d_in[0];
  const float* hidden = (const float*)d_in[1];
  const float* emb = (const float*)d_in[2];
  const float* Wr0 = (const float*)d_in[3];
  const float* Wz0 = (const float*)d_in[4];
  const float* Wh0 = (const float*)d_in[5];
  const float* WrR = (const float*)d_in[6];
  const float* WzR = (const float*)d_in[7];
  const float* WhR = (const float*)d_in[8];
  const float* brR = (const float*)d_in[9];
  const float* bzR = (const float*)d_in[10];
  const float* bhR = (const float*)d_in[11];
  const float* Ur = (const float*)d_in[12];
  const float* Uz = (const float*)d_in[13];
  const float* Uh = (const float*)d_in[14];
  const float* bur = (const float*)d_in[15];
  const float* buz = (const float*)d_in[16];
  const float* buh = (const float*)d_in[17];
  const float* Wout = (const float*)d_in[18];
  const float* bout = (const float*)d_in[19];
  float* out = (float*)d_out;

  char* ws = (char*)d_ws;
  size_t off = 0;
  auto alloc = [&](size_t bytes) -> void* {
    void* p = ws + off;
    off += (bytes + 255) & ~(size_t)255;
    return p;
  };
  u16* x_bf  = (u16*)alloc((size_t)TB * E_ * 2);        // 4 MB
  u16* W0cat = (u16*)alloc((size_t)3072 * 512 * 2);     // 3 MB
  u16* U0cat = (u16*)alloc((size_t)3072 * 1024 * 2);    // 6 MB
  u16* U1W   = (u16*)alloc((size_t)3072 * 2048 * 2);    // 12.6 MB
  u16* Woutb = (u16*)alloc((size_t)V_ * H_ * 2);        // 20.5 MB
  float* bias0 = (float*)alloc(3072 * 4);
  float* bias1 = (float*)alloc(3072 * 4);
  u16* XP    = (u16*)alloc((size_t)TB * 3072 * 2);      // 25 MB packed X
  u16* h0P   = (u16*)alloc((size_t)(T_ + 1) * BH * 2);  // 8.5 MB
  u16* h1P   = (u16*)alloc((size_t)(T_ + 1) * BH * 2);  // 8.5 MB
  u16* r0P   = (u16*)alloc((size_t)T_ * BH * 2);        // 8.4 MB
  u16* r1P   = (u16*)alloc((size_t)T_ * BH * 2);        // 8.4 MB
  int* bar   = (int*)alloc(4096);
  (void)ws_size; (void)in_sizes; (void)n_in; (void)out_size;

  hipMemsetAsync(bar, 0, 4096, stream);

  k_prepall<<<2048, 256, 0, stream>>>(Wr0, Wz0, Wh0, Ur, Uz, Uh, WrR, WzR, WhR, Wout,
                                      W0cat, U0cat, U1W, Woutb);
  k_gather<<<TB * E_ / 256, 256, 0, stream>>>(inputs, emb, x_bf);
  k_bias<<<12, 256, 0, stream>>>(bur, buz, buh, brR, bzR, bhR, bias0, bias1);
  k_init<<<256, 256, 0, stream>>>(hidden, h0P, h1P);

  // X = x_emb @ [Wr0|Wz0|Wh0]^T + bias0 -> packed-X bf16
  k_gemmX<<<dim3(32, 24), 256, 0, stream>>>(x_bf, W0cat, bias0, XP);
  // fused pipelined 2-layer recurrence
  k_recur2<<<128, 256, 0, stream>>>(U0cat, U1W, XP, bias1, hidden, h0P, h1P,
                                    r0P, r1P, bar, out + (size_t)TB * V_);
  // logits = h1_hist(packed) @ Wout^T + bout
  k_gemmL<<<dim3(32, 79), 256, 0, stream>>>(h1P + BH, Woutb, bout, out);
}

// Round 4
// 1834.626 us; speedup vs baseline: 1.8029x; 1.8029x over previous
//
#include <hip/hip_runtime.h>
#include <hip/hip_bf16.h>

#define T_ 64
#define B_ 64
#define E_ 512
#define H_ 1024
#define V_ 10000
#define TB 4096   // T_*B_
#define BH 65536  // B_*H_

typedef unsigned short u16;
typedef unsigned int u32;
typedef __attribute__((ext_vector_type(8))) short short8v;
typedef __attribute__((ext_vector_type(4))) float f32x4;

__device__ inline f32x4 mfma_bf16(short8v a, short8v b, f32x4 c) {
  return __builtin_amdgcn_mfma_f32_16x16x32_bf16(a, b, c, 0, 0, 0);
}

__device__ inline u16 f2bf(float f) {
  unsigned u = __float_as_uint(f);
  unsigned r = (u + 0x7fffu + ((u >> 16) & 1u)) >> 16;
  return (u16)r;
}
__device__ inline float bf2f(u16 h) { return __uint_as_float(((unsigned)h) << 16); }

// ---------------- prep ----------------

__global__ void k_prepall(const float* __restrict__ Wr0, const float* __restrict__ Wz0,
                          const float* __restrict__ Wh0, const float* __restrict__ Ur,
                          const float* __restrict__ Uz, const float* __restrict__ Uh,
                          const float* __restrict__ WrR, const float* __restrict__ WzR,
                          const float* __restrict__ WhR, const float* __restrict__ Wout,
                          u16* __restrict__ W0cat, u16* __restrict__ U0cat,
                          u16* __restrict__ U1W, u16* __restrict__ Woutb) {
  const int HE = H_ * E_;
  const int HH = H_ * H_;
  const size_t n0 = 3u * (size_t)HE;
  const size_t n1 = n0 + 3u * (size_t)HH;
  const size_t n2 = n1 + 3072u * 2048u;
  const size_t n3 = n2 + (size_t)V_ * H_;
  size_t i = (size_t)blockIdx.x * 256 + threadIdx.x;
  const size_t stride = (size_t)gridDim.x * 256;
  for (; i < n3; i += stride) {
    if (i < n0) {
      int g = (int)(i >> 19), off = (int)(i & (HE - 1));
      const float* s = g == 0 ? Wr0 : (g == 1 ? Wz0 : Wh0);
      W0cat[i] = f2bf(s[off]);
    } else if (i < n1) {
      size_t j = i - n0;
      int g = (int)(j >> 20), off = (int)(j & (HH - 1));
      const float* s = g == 0 ? Ur : (g == 1 ? Uz : Uh);
      U0cat[j] = f2bf(s[off]);
    } else if (i < n2) {
      size_t k = i - n1;
      int row = (int)(k >> 11), kk = (int)(k & 2047);
      int g = row >> 10, jj = row & 1023;
      const float* su = g == 0 ? Ur : (g == 1 ? Uz : Uh);
      const float* sw = g == 0 ? WrR : (g == 1 ? WzR : WhR);
      float v = (kk < 1024) ? su[(size_t)HH + (size_t)jj * 1024 + kk]
                            : sw[(size_t)jj * 1024 + (kk - 1024)];
      U1W[k] = f2bf(v);
    } else {
      size_t m = i - n2;
      Woutb[m] = f2bf(Wout[m]);
    }
  }
}

__global__ void k_gather(const int* __restrict__ idx, const float* __restrict__ emb,
                         u16* __restrict__ xbf) {
  int i = blockIdx.x * 256 + threadIdx.x;
  int row = i >> 9, e = i & 511;
  xbf[i] = f2bf(emb[(size_t)idx[row] * E_ + e]);
}

__global__ void k_bias(const float* __restrict__ bur, const float* __restrict__ buz,
                       const float* __restrict__ buh, const float* __restrict__ brR,
                       const float* __restrict__ bzR, const float* __restrict__ bhR,
                       float* __restrict__ bias0, float* __restrict__ bias1) {
  int j = blockIdx.x * 256 + threadIdx.x;
  int seg = j >> 10, col = j & 1023;
  float b0, b1;
  if (seg == 0)      { b0 = bur[col]; b1 = brR[col] + bur[H_ + col]; }
  else if (seg == 1) { b0 = buz[col]; b1 = bzR[col] + buz[H_ + col]; }
  else               { b0 = buh[col]; b1 = bhR[col] + buh[H_ + col]; }
  bias0[j] = b0; bias1[j] = b1;
}

// init packed hist slabs at t=0: dst[(j>>4)*1024 + row*16 + (j&15)]
__global__ void k_init(const float* __restrict__ hidden, u16* __restrict__ h0P,
                       u16* __restrict__ h1P) {
  int i = blockIdx.x * 256 + threadIdx.x;
  int row = i >> 10, j = i & 1023;
  int dst = ((j >> 4) << 10) + (row << 4) + (j & 15);
  h0P[dst] = f2bf(hidden[i]);
  h1P[dst] = f2bf(hidden[BH + i]);
}

// ---------------- GEMM 1: X = x_emb @ W0cat^T + bias0, packed-X bf16 out ----------------

__global__ __launch_bounds__(256, 2) void k_gemmX(const u16* __restrict__ A,
                                                  const u16* __restrict__ Wt,
                                                  const float* __restrict__ bias,
                                                  u16* __restrict__ XP) {
  const int m0 = blockIdx.x * 128, n0 = blockIdx.y * 128;
  const int wid = threadIdx.x >> 6, lane = threadIdx.x & 63;
  const int wm = wid >> 1, wn = wid & 1;
  const int lrow = lane & 15, lk = (lane >> 4) * 8;
  f32x4 acc[4][4] = {};
  const u16* Ab = A + (size_t)(m0 + wm * 64 + lrow) * 512 + lk;
  const u16* Wb = Wt + (size_t)(n0 + wn * 64 + lrow) * 512 + lk;
  for (int ks = 0; ks < 512; ks += 32) {
    short8v a[4], b[4];
#pragma unroll
    for (int f = 0; f < 4; f++) a[f] = *(const short8v*)(Ab + (size_t)f * 16 * 512 + ks);
#pragma unroll
    for (int f = 0; f < 4; f++) b[f] = *(const short8v*)(Wb + (size_t)f * 16 * 512 + ks);
#pragma unroll
    for (int i = 0; i < 4; i++)
#pragma unroll
      for (int j = 0; j < 4; j++) acc[i][j] = mfma_bf16(a[i], b[j], acc[i][j]);
  }
  const int drow0 = (lane >> 4) * 4, dcol = lane & 15;
#pragma unroll
  for (int i = 0; i < 4; i++)
#pragma unroll
    for (int j = 0; j < 4; j++) {
      int col = n0 + wn * 64 + j * 16 + dcol;
      float bv = bias[col];
      int g = col >> 10, cg = (col & 1023) >> 4, cc = col & 15;
#pragma unroll
      for (int v = 0; v < 4; v++) {
        int row = m0 + wm * 64 + i * 16 + drow0 + v;
        int t = row >> 6, rr = row & 63;
        XP[(((size_t)t * 64 + cg) * 64 + rr) * 48 + g * 16 + cc] = f2bf(acc[i][j][v] + bv);
      }
    }
}

// ---------------- GEMM 2: logits = h1P(packed) @ Woutb^T + bout ----------------

__global__ __launch_bounds__(256, 2) void k_gemmL(const u16* __restrict__ AP,
                                                  const u16* __restrict__ Wt,
                                                  const float* __restrict__ bias,
                                                  float* __restrict__ C) {
  const int m0 = blockIdx.x * 128, n0 = blockIdx.y * 128;
  const int wid = threadIdx.x >> 6, lane = threadIdx.x & 63;
  const int wm = wid >> 1, wn = wid & 1;
  const int lrow = lane & 15, lk = (lane >> 4) * 8;
  const int lkb = lk >> 4, lkc = lk & 15;
  f32x4 acc[4][4] = {};
  const int rowhi = (m0 + wm * 64) >> 6;
  const u16* Ab = AP + (size_t)rowhi * BH + (size_t)lkb * 1024 + lrow * 16 + lkc;
  const u16* Wb = Wt + (size_t)(n0 + wn * 64 + lrow) * 1024 + lk;
  bool nvalid[4];
#pragma unroll
  for (int f = 0; f < 4; f++) nvalid[f] = (n0 + wn * 64 + f * 16 + lrow) < V_;
  const short8v zv = {};
  for (int ks = 0; ks < 1024; ks += 32) {
    short8v a[4], b[4];
#pragma unroll
    for (int f = 0; f < 4; f++) a[f] = *(const short8v*)(Ab + ks * 64 + f * 256);
#pragma unroll
    for (int f = 0; f < 4; f++)
      b[f] = nvalid[f] ? *(const short8v*)(Wb + (size_t)f * 16 * 1024 + ks) : zv;
#pragma unroll
    for (int i = 0; i < 4; i++)
#pragma unroll
      for (int j = 0; j < 4; j++) acc[i][j] = mfma_bf16(a[i], b[j], acc[i][j]);
  }
  const int drow0 = (lane >> 4) * 4, dcol = lane & 15;
#pragma unroll
  for (int i = 0; i < 4; i++)
#pragma unroll
    for (int j = 0; j < 4; j++) {
      int col = n0 + wn * 64 + j * 16 + dcol;
      if (col >= V_) continue;
      float bv = bias[col];
#pragma unroll
      for (int v = 0; v < 4; v++) {
        int row = m0 + wm * 64 + i * 16 + drow0 + v;
        C[(size_t)row * V_ + col] = acc[i][j][v] + bv;
      }
    }
}

// ---------------- fused 2-layer pipelined recurrence, LDS-resident weights ----------------
// 256 blocks x 128 thr (2 waves x 16 rows). Block = (layer, colgroup cg 0-63, rowhalf rh 0-1):
// covers rows rh*32..+31, cols cg*16..+15. L0: Wr|Wz|Wh in LDS (96KB, K=1024).
// L1: Wr|Wz in LDS (128KB, K=2048), Wh streamed from global (L2-hot).
// LDS 16B-chunk XOR swizzle (chunk ^ (col&7)) -> conflict-free ds_read_b128.
// Cross-block publishes: packed per-colgroup tiles, relaxed agent atomics.

__device__ inline void gbar(int* bar, int& phase) {
  asm volatile("s_waitcnt vmcnt(0)" ::: "memory");
  __syncthreads();
  ++phase;
  const int tid = threadIdx.x;
  const int gbid = blockIdx.x;
  if (tid == 0)
    __hip_atomic_fetch_add(bar + (gbid & 7) * 32, 1, __ATOMIC_RELAXED,
                           __HIP_MEMORY_SCOPE_AGENT);
  if (gbid == 0) {
    if (tid < 64) {
      const int need = 32 * phase;  // 32 blocks per group
      bool done;
      do {
        int c = (tid < 8) ? __hip_atomic_load(bar + tid * 32, __ATOMIC_RELAXED,
                                              __HIP_MEMORY_SCOPE_AGENT)
                          : need;
        done = __all(c >= need);
        if (!done) __builtin_amdgcn_s_sleep(1);
      } while (!done);
      if (tid == 0)
        __hip_atomic_store(bar + 512, phase, __ATOMIC_RELAXED, __HIP_MEMORY_SCOPE_AGENT);
    }
  } else if (tid == 0) {
    while (__hip_atomic_load(bar + 512, __ATOMIC_RELAXED, __HIP_MEMORY_SCOPE_AGENT) < phase)
      __builtin_amdgcn_s_sleep(1);
  }
  __syncthreads();
}

__global__ __launch_bounds__(128, 1) void k_recur2(
    const u16* __restrict__ U0, const u16* __restrict__ U1W,
    const u16* __restrict__ XP, const float* __restrict__ bias1,
    const float* __restrict__ hidden,
    u16* __restrict__ h0P, u16* __restrict__ h1P,
    u16* __restrict__ r0P, u16* __restrict__ r1P,
    int* __restrict__ bar, float* __restrict__ hfin) {
  __shared__ __align__(16) u16 wlds[65536];  // 128 KiB

  const int tid = threadIdx.x, gbid = blockIdx.x;
  const int lay = gbid >> 7;
  const int sub = gbid & 127;
  const int cg = sub & 63, rhf = sub >> 6;
  const int jr = cg * 16;
  const int rowbase = rhf * 32;
  const int wid = tid >> 6, lane = tid & 63;
  const int lrow = lane & 15, lk = (lane >> 4) * 8;
  const int lk3 = lk >> 3;
  const int x7 = lrow & 7;
  const int drow0 = (lane >> 4) * 4, dcol = lane & 15;
  const int KLS = lay ? 11 : 10;  // log2(K per LDS row)
  u16* histL = lay ? h1P : h0P;
  u16* rhL = lay ? r1P : r0P;

  // ---- stage weights into LDS (swizzled) ----
  {
    const u16* Wg = lay ? U1W : U0;
    const int lCPR = lay ? 8 : 7;       // log2(chunks per row)
    const int NG = lay ? 2 : 3;         // gates in LDS
    const int total = NG << (4 + lCPR); // NG*16*CPR
    const int KL = 1 << KLS;
    for (int idx = tid; idx < total; idx += 128) {
      int r16 = idx >> lCPR;
      int ch = idx & ((1 << lCPR) - 1);
      int g = r16 >> 4, r = r16 & 15;
      short8v v = *(const short8v*)(Wg + (size_t)((g << 10) + jr + r) * KL + (ch << 3));
      *(short8v*)&wlds[((size_t)r16 << KLS) + ((ch ^ (r & 7)) << 3)] = v;
    }
  }
  __syncthreads();

  const int lbR = lrow << KLS;
  const int lbZ = (16 + lrow) << KLS;
  const int lbH = (32 + lrow) << KLS;  // layer 0 only
  const u16* Whg = U1W + (size_t)(2048 + jr + lrow) * 2048 + lk;  // layer 1 Wh (global)

  const int abase = (lk >> 4) * 1024 + (rowbase + wid * 16 + lrow) * 16 + (lk & 15);
  const int orow = rowbase + wid * 16 + drow0;  // this lane's output rows orow..orow+3

  float hreg[4];
#pragma unroll
  for (int v = 0; v < 4; v++)
    hreg[v] = hidden[(size_t)lay * BH + (size_t)(orow + v) * 1024 + jr + dcol];

  float bR = 0.f, bZ = 0.f, bH = 0.f;
  if (lay) {
    bR = bias1[jr + dcol];
    bZ = bias1[1024 + jr + dcol];
    bH = bias1[2048 + jr + dcol];
  }

  int phase = 0;
  for (int p = 0; p <= T_; p++) {
    const int t = lay ? (p - 1) : p;
    const bool act = (t >= 0) && (t < T_);
    float zreg[4], xh[4];
    if (act) {
      float xr[4], xz[4];
      if (!lay) {
        const u16* xb = XP + (((size_t)t * 64 + cg) * 64 + orow) * 48 + dcol;
#pragma unroll
        for (int v = 0; v < 4; v++) {
          xr[v] = bf2f(xb[v * 48]);
          xz[v] = bf2f(xb[v * 48 + 16]);
          xh[v] = bf2f(xb[v * 48 + 32]);
        }
      } else {
#pragma unroll
        for (int v = 0; v < 4; v++) { xr[v] = bR; xz[v] = bZ; xh[v] = bH; }
      }
      // ---------- stage A: r,z gates ----------
      f32x4 ar = {}, az = {};
      if (!lay) {
        const u16* Ab = h0P + (size_t)t * BH + abase;
#pragma unroll
        for (int kk = 0; kk < 1024; kk += 32) {
          short8v a = *(const short8v*)(Ab + kk * 64);
          int sw = (((kk >> 3) + lk3) ^ x7) << 3;
          ar = mfma_bf16(a, *(short8v*)&wlds[lbR + sw], ar);
          az = mfma_bf16(a, *(short8v*)&wlds[lbZ + sw], az);
        }
      } else {
        const u16* Ab1 = h1P + (size_t)t * BH + abase;
        const u16* Ab0 = h0P + (size_t)(t + 1) * BH + abase;
#pragma unroll
        for (int kk = 0; kk < 1024; kk += 32) {
          short8v a = *(const short8v*)(Ab1 + kk * 64);
          int sw = (((kk >> 3) + lk3) ^ x7) << 3;
          ar = mfma_bf16(a, *(short8v*)&wlds[lbR + sw], ar);
          az = mfma_bf16(a, *(short8v*)&wlds[lbZ + sw], az);
        }
#pragma unroll
        for (int kk = 0; kk < 1024; kk += 32) {
          short8v a = *(const short8v*)(Ab0 + kk * 64);
          int sw = ((128 + (kk >> 3) + lk3) ^ x7) << 3;
          ar = mfma_bf16(a, *(short8v*)&wlds[lbR + sw], ar);
          az = mfma_bf16(a, *(short8v*)&wlds[lbZ + sw], az);
        }
      }
      u16* rtile = rhL + (size_t)t * BH + (size_t)cg * 1024;
#pragma unroll
      for (int v = 0; v < 4; v++) {
        float r = 1.f / (1.f + __expf(-(ar[v] + xr[v])));
        float z = 1.f / (1.f + __expf(-(az[v] + xz[v])));
        zreg[v] = z;
        u16 me = f2bf(r * hreg[v]);
        int oth = __shfl_xor((int)me, 1);
        if (!(dcol & 1)) {
          u32 pk = (u32)me | ((u32)(u16)oth << 16);
          __hip_atomic_store((u32*)(rtile + (orow + v) * 16 + dcol), pk,
                             __ATOMIC_RELAXED, __HIP_MEMORY_SCOPE_AGENT);
        }
      }
    }
    gbar(bar, phase);
    if (act) {
      // ---------- stage B: candidate + state update ----------
      f32x4 ah = {};
      if (!lay) {
        const u16* Ab = r0P + (size_t)t * BH + abase;
#pragma unroll
        for (int kk = 0; kk < 1024; kk += 32) {
          short8v a = *(const short8v*)(Ab + kk * 64);
          int sw = (((kk >> 3) + lk3) ^ x7) << 3;
          ah = mfma_bf16(a, *(short8v*)&wlds[lbH + sw], ah);
        }
      } else {
        const u16* Ab1 = r1P + (size_t)t * BH + abase;
        const u16* Ab0 = h0P + (size_t)(t + 1) * BH + abase;
#pragma unroll
        for (int kk = 0; kk < 1024; kk += 32) {
          short8v a = *(const short8v*)(Ab1 + kk * 64);
          short8v b = *(const short8v*)(Whg + kk);
          ah = mfma_bf16(a, b, ah);
        }
#pragma unroll
        for (int kk = 0; kk < 1024; kk += 32) {
          short8v a = *(const short8v*)(Ab0 + kk * 64);
          short8v b = *(const short8v*)(Whg + 1024 + kk);
          ah = mfma_bf16(a, b, ah);
        }
      }
      u16* htile = histL + (size_t)(t + 1) * BH + (size_t)cg * 1024;
#pragma unroll
      for (int v = 0; v < 4; v++) {
        float th = tanhf(ah[v] + xh[v]);
        float hn = (1.f - zreg[v]) * hreg[v] + zreg[v] * th;
        hreg[v] = hn;
        u16 me = f2bf(hn);
        int oth = __shfl_xor((int)me, 1);
        if (!(dcol & 1)) {
          u32 pk = (u32)me | ((u32)(u16)oth << 16);
          __hip_atomic_store((u32*)(htile + (orow + v) * 16 + dcol), pk,
                             __ATOMIC_RELAXED, __HIP_MEMORY_SCOPE_AGENT);
        }
        if (t == T_ - 1)
          hfin[(size_t)lay * BH + (size_t)(orow + v) * 1024 + jr + dcol] = hn;
      }
    }
    gbar(bar, phase);
  }
}

// ---------------- launcher ----------------

extern "C" void kernel_launch(void* const* d_in, const int* in_sizes, int n_in,
                              void* d_out, int out_size, void* d_ws, size_t ws_size,
                              hipStream_t stream) {
  const int* inputs = (const int*)d_in[0];
  const float* hidden = (const float*)d_in[1];
  const float* emb = (const float*)d_in[2];
  const float* Wr0 = (const float*)d_in[3];
  const float* Wz0 = (const float*)d_in[4];
  const float* Wh0 = (const float*)d_in[5];
  const float* WrR = (const float*)d_in[6];
  const float* WzR = (const float*)d_in[7];
  const float* WhR = (const float*)d_in[8];
  const float* brR = (const float*)d_in[9];
  const float* bzR = (const float*)d_in[10];
  const float* bhR = (const float*)d_in[11];
  const float* Ur = (const float*)d_in[12];
  const float* Uz = (const float*)d_in[13];
  const float* Uh = (const float*)d_in[14];
  const float* bur = (const float*)d_in[15];
  const float* buz = (const float*)d_in[16];
  const float* buh = (const float*)d_in[17];
  const float* Wout = (const float*)d_in[18];
  const float* bout = (const float*)d_in[19];
  float* out = (float*)d_out;

  char* ws = (char*)d_ws;
  size_t off = 0;
  auto alloc = [&](size_t bytes) -> void* {
    void* p = ws + off;
    off += (bytes + 255) & ~(size_t)255;
    return p;
  };
  u16* x_bf  = (u16*)alloc((size_t)TB * E_ * 2);
  u16* W0cat = (u16*)alloc((size_t)3072 * 512 * 2);
  u16* U0cat = (u16*)alloc((size_t)3072 * 1024 * 2);
  u16* U1W   = (u16*)alloc((size_t)3072 * 2048 * 2);
  u16* Woutb = (u16*)alloc((size_t)V_ * H_ * 2);
  float* bias0 = (float*)alloc(3072 * 4);
  float* bias1 = (float*)alloc(3072 * 4);
  u16* XP    = (u16*)alloc((size_t)TB * 3072 * 2);
  u16* h0P   = (u16*)alloc((size_t)(T_ + 1) * BH * 2);
  u16* h1P   = (u16*)alloc((size_t)(T_ + 1) * BH * 2);
  u16* r0P   = (u16*)alloc((size_t)T_ * BH * 2);
  u16* r1P   = (u16*)alloc((size_t)T_ * BH * 2);
  int* bar   = (int*)alloc(4096);
  (void)ws_size; (void)in_sizes; (void)n_in; (void)out_size;

  hipMemsetAsync(bar, 0, 4096, stream);

  k_prepall<<<2048, 256, 0, stream>>>(Wr0, Wz0, Wh0, Ur, Uz, Uh, WrR, WzR, WhR, Wout,
                                      W0cat, U0cat, U1W, Woutb);
  k_gather<<<TB * E_ / 256, 256, 0, stream>>>(inputs, emb, x_bf);
  k_bias<<<12, 256, 0, stream>>>(bur, buz, buh, brR, bzR, bhR, bias0, bias1);
  k_init<<<256, 256, 0, stream>>>(hidden, h0P, h1P);

  k_gemmX<<<dim3(32, 24), 256, 0, stream>>>(x_bf, W0cat, bias0, XP);
  k_recur2<<<256, 128, 0, stream>>>(U0cat, U1W, XP, bias1, hidden, h0P, h1P,
                                    r0P, r1P, bar, out + (size_t)TB * V_);
  k_gemmL<<<dim3(32, 79), 256, 0, stream>>>(h1P + BH, Woutb, bout, out);
}